// Round 9
// baseline (224.158 us; speedup 1.0000x reference)
//
#include <hip/hip_runtime.h>

typedef __bf16 bf16;
typedef __bf16 bf16x4 __attribute__((ext_vector_type(4)));
typedef __bf16 bf16x8 __attribute__((ext_vector_type(8)));
typedef float f32x4 __attribute__((ext_vector_type(4)));
typedef short s16x4 __attribute__((ext_vector_type(4)));
typedef unsigned int u32;
typedef unsigned long long u64;

#define B_ 2
#define H_ 8
#define L_ 2048
#define D_ 128
#define F_ 128
#define QT 64
#define KT 64
#define NKT (L_ / KT)
#define NQT (L_ / QT)

// workspace layout (bytes)
#define WS_KB 0u            // Kb  : bf16 frag-blocks [b][kt][kti*4+kc][lane]x16B, 1 MB
#define WS_VT (1u << 20)    // Vtb : bf16 frag-blocks [b][kt][fi*2+kp][lane]x16B, 1 MB
#define WS_MB (2u << 20)    // bits: u64 [b][q][kt], 1 MB

// LDS (epilogue only; main loop uses NO LDS):
//  pOx @0 f32[64][132]=33792 ; sO2t @0 bf16[128][136]=34816 (after pOx consumed)
//  sOh @34816 bf16[64][136]=17408 (ends 52224) ; lws @52224 (512 B)
#define SMEM_BYTES 52736
#define POX_STRIDE 132
#define SOH_OFF 34816
#define SOH_STRIDE 136
#define SO2_STRIDE 136
#define LWS_OFF 52224

__device__ __forceinline__ f32x4 mfma32(bf16x8 a, bf16x8 b, f32x4 c) {
    return __builtin_amdgcn_mfma_f32_16x16x32_bf16(a, b, c, 0, 0, 0);
}

__device__ __forceinline__ f32x4 mfma16(bf16x4 a, bf16x4 b, f32x4 c) {
#if __has_builtin(__builtin_amdgcn_mfma_f32_16x16x16_bf16)
    return __builtin_amdgcn_mfma_f32_16x16x16_bf16(a, b, c, 0, 0, 0);
#else
    s16x4 as = __builtin_bit_cast(s16x4, a);
    s16x4 bs = __builtin_bit_cast(s16x4, b);
    return __builtin_amdgcn_mfma_f32_16x16x16bf16_1k(as, bs, c, 0, 0, 0);
#endif
}

__device__ __forceinline__ float fast_exp2(float x) {
#if __has_builtin(__builtin_amdgcn_exp2f)
    return __builtin_amdgcn_exp2f(x);
#else
    return exp2f(x);
#endif
}

// ---- fused prep ----
// blocks 0..8191      : mask -> bitpacked u64
// blocks 8192..8255   : K -> per-fragment lane-contiguous bf16 blocks (64 tiles)
// blocks 8256..8319   : V -> per-fragment lane-contiguous bf16 pair blocks (64 tiles)
__global__ __launch_bounds__(256)
void prep_all(const float* __restrict__ XK, const float* __restrict__ XV,
              const int* __restrict__ mask, bf16* __restrict__ Kb,
              bf16* __restrict__ Vtb, u64* __restrict__ bits)
{
    const int bid = blockIdx.x;
    const int tid = threadIdx.x;
    if (bid < 8192) {
        int wv = bid * 4 + (tid >> 6);
        int lane = tid & 63;
        size_t base = (size_t)wv * 256;
        #pragma unroll
        for (int s = 0; s < 4; ++s) {
            int m = mask[base + s * 64 + lane];
            u64 bal = __ballot(m != 0);
            if (lane == 0) bits[(size_t)wv * 4 + s] = bal;
        }
    } else if (bid < 8256) {
        // K fragment blocks: tile = b*32+kt; frag = kti*4+kc; lane (c,quad); 16B:
        //   K[kt*64 + kti*16 + c][kc*32 + quad*8 + j], j=0..7
        int tile = bid - 8192;
        int bb = tile >> 5, kt = tile & 31;
        #pragma unroll
        for (int i = 0; i < 4; ++i) {
            int idx  = tid * 4 + i;            // 0..1023
            int frag = idx >> 6;               // kti*4+kc
            int lane = idx & 63;
            int c = lane & 15, quad = lane >> 4;
            int kti = frag >> 2, kc = frag & 3;
            const float* src = XK + (size_t)(bb * L_ + kt * 64 + kti * 16 + c) * D_
                               + kc * 32 + quad * 8;
            float4 v0 = *(const float4*)src;
            float4 v1 = *(const float4*)(src + 4);
            bf16x8 w;
            w[0] = (bf16)v0.x; w[1] = (bf16)v0.y; w[2] = (bf16)v0.z; w[3] = (bf16)v0.w;
            w[4] = (bf16)v1.x; w[5] = (bf16)v1.y; w[6] = (bf16)v1.z; w[7] = (bf16)v1.w;
            *(bf16x8*)(Kb + (size_t)tile * 8192 + frag * 512 + lane * 8) = w;
        }
    } else {
        // V pair blocks: frag = fi*2+kp; lane (c,quad); 16B:
        //   j<4 : V[kt*64 + (2kp)*16   + quad*4 + j][fi*16 + c]
        //   j>=4: V[kt*64 + (2kp+1)*16 + quad*4 + (j-4)][fi*16 + c]
        int tile = bid - 8256;
        int bb = tile >> 5, kt = tile & 31;
        #pragma unroll
        for (int i = 0; i < 4; ++i) {
            int idx  = tid * 4 + i;
            int frag = idx >> 6;               // fi*2+kp
            int lane = idx & 63;
            int c = lane & 15, quad = lane >> 4;
            int fi = frag >> 1, kp = frag & 1;
            const float* src = XV + (size_t)(bb * L_ + kt * 64 + kp * 32 + quad * 4) * F_
                               + fi * 16 + c;
            bf16x8 w;
            #pragma unroll
            for (int j = 0; j < 4; ++j) {
                w[j]     = (bf16)src[(size_t)j * F_];
                w[4 + j] = (bf16)src[(size_t)(16 + j) * F_];
            }
            *(bf16x8*)(Vtb + (size_t)tile * 8192 + frag * 512 + lane * 8) = w;
        }
    }
}

// ---- main fused kernel: 512 thr / 8 waves; wave = (msel, kslice), NO main-loop
//      barriers, NO main-loop LDS: fragments stream global->L1->VGPR->MFMA ----
__global__ __launch_bounds__(512, 4)
void attn_fused_kernel(const float* __restrict__ XQ, const bf16* __restrict__ Kb,
                       const bf16* __restrict__ Vtb, const u64* __restrict__ bits,
                       const float* __restrict__ WQ, const float* __restrict__ WK,
                       const float* __restrict__ WV, const float* __restrict__ Om,
                       float* __restrict__ out)
{
    __shared__ __align__(16) char smem[SMEM_BYTES];
    __shared__ __align__(16) float g_s[128];

    float* pOx = (float*)smem;
    bf16* sO2t = (bf16*)smem;                  // after pOx consumed
    bf16* sOh  = (bf16*)(smem + SOH_OFF);
    float* lws = (float*)(smem + LWS_OFF);

    const int tid  = threadIdx.x;
    const int wave = tid >> 6;        // 0..7
    const int lane = tid & 63;
    const int c    = lane & 15;
    const int quad = lane >> 4;
    const int qt = blockIdx.x, h = blockIdx.y, b = blockIdx.z;
    const int q0 = qt * QT;

    const int msel   = wave & 3;      // m-tile (16 q rows)
    const int kslice = wave >> 2;     // k-tile parity
    const int fv  = tid & 127;
    const int grp = tid >> 7;

    // g = diag(WQ)*diag(WK)/sqrt(D) * log2(e)
    if (tid < 128) {
        float wq = WQ[(h * D_ + tid) * D_ + tid];
        float wk = WK[(h * D_ + tid) * D_ + tid];
        g_s[tid] = wq * wk * 0.12752230502179406f;
    }
    __syncthreads();

    const char* gK = (const char*)Kb + (size_t)b * 524288;   // 16 KB per tile
    const char* gV = (const char*)Vtb + (size_t)b * 524288;

    // Q fragments (B-operand), scaled, loop-invariant
    bf16x8 qfrag[4];
    {
        const float* qrow = XQ + (size_t)(b * L_ + q0 + msel * 16 + c) * D_;
        #pragma unroll
        for (int kc = 0; kc < 4; ++kc) {
            int d0 = kc * 32 + quad * 8;
            float4 v0 = *(const float4*)(qrow + d0);
            float4 v1 = *(const float4*)(qrow + d0 + 4);
            float4 g0 = *(const float4*)(g_s + d0);
            float4 g1 = *(const float4*)(g_s + d0 + 4);
            bf16x8 w;
            w[0] = (bf16)(v0.x * g0.x); w[1] = (bf16)(v0.y * g0.y);
            w[2] = (bf16)(v0.z * g0.z); w[3] = (bf16)(v0.w * g0.w);
            w[4] = (bf16)(v1.x * g1.x); w[5] = (bf16)(v1.y * g1.y);
            w[6] = (bf16)(v1.z * g1.z); w[7] = (bf16)(v1.w * g1.w);
            qfrag[kc] = w;
        }
    }

    f32x4 oacc[8];                     // O partial: 16m x 128f over wave's k-slice
    #pragma unroll
    for (int fi = 0; fi < 8; ++fi)
        #pragma unroll
        for (int r = 0; r < 4; ++r) oacc[fi][r] = 0.f;
    float lsum = 0.f;

    const u64* mrow = bits + (size_t)(b * L_ + q0 + msel * 16 + c) * NKT;

    for (int it = 0; it < 16; ++it) {
        const int kt = kslice + 2 * it;
        const bf16* kb = (const bf16*)(gK + (size_t)kt * 16384);
        const bf16* vb = (const bf16*)(gV + (size_t)kt * 16384);
        u64 mb = mrow[kt];

        // S^T = K @ Qg^T : 16 coalesced b128 fragment loads, 16 mfma32
        f32x4 tacc[4];
        #pragma unroll
        for (int kti = 0; kti < 4; ++kti)
            #pragma unroll
            for (int r = 0; r < 4; ++r) tacc[kti][r] = 0.f;

        #pragma unroll
        for (int kti = 0; kti < 4; ++kti) {
            bf16x8 kf[4];
            #pragma unroll
            for (int kc = 0; kc < 4; ++kc)
                kf[kc] = *(const bf16x8*)(kb + (kti * 4 + kc) * 512 + lane * 8);
            #pragma unroll
            for (int kc = 0; kc < 4; ++kc)
                tacc[kti] = mfma32(kf[kc], qfrag[kc], tacc[kti]);
        }

        // mask + exp2 -> P directly in mfma16 A-operand layout (registers)
        bf16x4 pf[4];
        #pragma unroll
        for (int kti = 0; kti < 4; ++kti) {
            #pragma unroll
            for (int r = 0; r < 4; ++r) {
                int pos = kti * 16 + quad * 4 + r;
                float p = ((mb >> pos) & 1ull) ? fast_exp2(tacc[kti][r]) : 0.f;
                lsum += p;
                pf[kti][r] = (bf16)p;
            }
        }

        // O += P @ V : 16 coalesced b128 pair loads, 32 mfma16
        #pragma unroll
        for (int fi = 0; fi < 8; ++fi) {
            bf16x8 vp0 = *(const bf16x8*)(vb + (fi * 2 + 0) * 512 + lane * 8);
            bf16x8 vp1 = *(const bf16x8*)(vb + (fi * 2 + 1) * 512 + lane * 8);
            bf16x4 a0 = __builtin_shufflevector(vp0, vp0, 0, 1, 2, 3);
            bf16x4 a1 = __builtin_shufflevector(vp0, vp0, 4, 5, 6, 7);
            bf16x4 a2 = __builtin_shufflevector(vp1, vp1, 0, 1, 2, 3);
            bf16x4 a3 = __builtin_shufflevector(vp1, vp1, 4, 5, 6, 7);
            oacc[fi] = mfma16(pf[0], a0, oacc[fi]);
            oacc[fi] = mfma16(pf[1], a1, oacc[fi]);
            oacc[fi] = mfma16(pf[2], a2, oacc[fi]);
            oacc[fi] = mfma16(pf[3], a3, oacc[fi]);
        }
    }

    // publish per-wave row sums (lane c holds row m=msel*16+c after quad-reduce)
    {
        float v = lsum;
        v += __shfl_xor(v, 16); v += __shfl_xor(v, 32);
        if (lane < 16) lws[wave * 16 + lane] = v;
    }
    if (tid < 128)
        g_s[tid] = WV[(h * F_ + tid) * F_ + tid];   // dv
    __syncthreads();

    // kslice=1 waves dump partial O (f32)
    if (kslice == 1) {
        #pragma unroll
        for (int fi = 0; fi < 8; ++fi)
            #pragma unroll
            for (int r = 0; r < 4; ++r)
                pOx[(msel * 16 + quad * 4 + r) * POX_STRIDE + fi * 16 + c] = oacc[fi][r];
    }
    __syncthreads();

    // kslice=0 waves: combine, normalize, write Oh (bf16)
    if (kslice == 0) {
        float linv[4];
        #pragma unroll
        for (int r = 0; r < 4; ++r) {
            int s = quad * 4 + r;
            linv[r] = 1.0f / (lws[msel * 16 + s] + lws[(4 + msel) * 16 + s]);
        }
        #pragma unroll
        for (int fi = 0; fi < 8; ++fi)
            #pragma unroll
            for (int r = 0; r < 4; ++r) {
                int row = msel * 16 + quad * 4 + r;
                float v = (oacc[fi][r] + pOx[row * POX_STRIDE + fi * 16 + c]) * linv[r];
                sOh[row * SOH_STRIDE + fi * 16 + c] = (bf16)v;
            }
    }
    __syncthreads();   // pOx consumed -> sO2t region free

    // stage O2^T: sO2t[f][f'] = O[h*128+f'][f] * dv[f']
    #pragma unroll
    for (int i = 0; i < 8; ++i) {
        int fp4 = grp * 32 + i * 4;
        bf16x4 w;
        #pragma unroll
        for (int j = 0; j < 4; ++j) {
            int x = fp4 + j;
            w[j] = (bf16)(Om[(h * F_ + x) * F_ + fv] * g_s[x]);
        }
        *(bf16x4*)(sO2t + fv * SO2_STRIDE + fp4) = w;
    }
    __syncthreads();

    // out_partial = Oh @ O2 (64x128x128): wave (pm, pf), atomic over heads
    const int pm = wave & 3;
    const int pf = wave >> 2;
    bf16x8 afr[4];
    const bf16* ohrow = sOh + (pm * 16 + c) * SOH_STRIDE;
    #pragma unroll
    for (int kc = 0; kc < 4; ++kc)
        afr[kc] = *(const bf16x8*)(ohrow + kc * 32 + quad * 8);

    #pragma unroll
    for (int nt = 0; nt < 4; ++nt) {
        f32x4 pacc;
        #pragma unroll
        for (int r = 0; r < 4; ++r) pacc[r] = 0.f;
        const bf16* orow = sO2t + ((pf * 4 + nt) * 16 + c) * SO2_STRIDE;
        #pragma unroll
        for (int kc = 0; kc < 4; ++kc) {
            bf16x8 bfrag = *(const bf16x8*)(orow + kc * 32 + quad * 8);
            pacc = mfma32(afr[kc], bfrag, pacc);
        }
        #pragma unroll
        for (int r = 0; r < 4; ++r) {
            int qg = q0 + pm * 16 + quad * 4 + r;
            atomicAdd(out + ((size_t)(b * L_ + qg) * F_ + (pf * 4 + nt) * 16 + c), pacc[r]);
        }
    }
}

extern "C" void kernel_launch(void* const* d_in, const int* in_sizes, int n_in,
                              void* d_out, int out_size, void* d_ws, size_t ws_size,
                              hipStream_t stream) {
    const float* XQ   = (const float*)d_in[0];
    const float* XK   = (const float*)d_in[1];
    const float* XV   = (const float*)d_in[2];
    const int*   mask = (const int*)d_in[3];
    const float* WQ   = (const float*)d_in[4];
    const float* WK   = (const float*)d_in[5];
    const float* WV   = (const float*)d_in[6];
    const float* Om   = (const float*)d_in[7];
    float* out = (float*)d_out;

    char* ws = (char*)d_ws;
    bf16* Kb   = (bf16*)(ws + WS_KB);
    bf16* Vtb  = (bf16*)(ws + WS_VT);
    u64*  bits = (u64*)(ws + WS_MB);

    prep_all<<<8320, 256, 0, stream>>>(XK, XV, mask, Kb, Vtb, bits);
    hipMemsetAsync(out, 0, (size_t)out_size * sizeof(float), stream);

    dim3 grid(NQT, H_, B_);
    attn_fused_kernel<<<grid, 512, 0, stream>>>(XQ, Kb, Vtb, bits, WQ, WK, WV, Om, out);
}

// Round 10
// 165.475 us; speedup vs baseline: 1.3546x; 1.3546x over previous
//
#include <hip/hip_runtime.h>

typedef __bf16 bf16;
typedef __bf16 bf16x4 __attribute__((ext_vector_type(4)));
typedef __bf16 bf16x8 __attribute__((ext_vector_type(8)));
typedef float f32x4 __attribute__((ext_vector_type(4)));
typedef short s16x4 __attribute__((ext_vector_type(4)));
typedef unsigned int u32;
typedef unsigned long long u64;

#define B_ 2
#define H_ 8
#define L_ 2048
#define D_ 128
#define F_ 128
#define QT 64
#define KT 64
#define NKT (L_ / KT)

// workspace layout (bytes)
#define WS_KB 0u            // Kb  : bf16 [b][k][16B-chunk swizzled], 1 MB
#define WS_VT (1u << 20)    // Vtb : bf16 tiles [b][kt][f][4-elem group swz], 1 MB
#define WS_MB (2u << 20)    // bits: u64 [b][q][kt], 1 MB

// LDS main: sK0@0 sK1@16384 sV0@32768 sV1@49152 (16 KB each), lws@65536 (512 B)
// epilogue: pOx@0 f32[64][132]=33792 ; sOh@36864 bf16[64][136]=17408 (ends 54272);
//           sO2t@0 bf16[128][136]=34816 (after pOx consumed) ; lws preserved.
#define SMEM_BYTES 66048
#define LWS_OFF 65536
#define POX_STRIDE 132
#define SOH_OFF 36864
#define SOH_STRIDE 136
#define SO2_STRIDE 136

__device__ __forceinline__ void dma16(const void* g, void* l) {
    __builtin_amdgcn_global_load_lds(
        (const __attribute__((address_space(1))) u32*)g,
        (__attribute__((address_space(3))) u32*)l, 16, 0, 0);
}

__device__ __forceinline__ f32x4 mfma32(bf16x8 a, bf16x8 b, f32x4 c) {
    return __builtin_amdgcn_mfma_f32_16x16x32_bf16(a, b, c, 0, 0, 0);
}

__device__ __forceinline__ f32x4 mfma16(bf16x4 a, bf16x4 b, f32x4 c) {
#if __has_builtin(__builtin_amdgcn_mfma_f32_16x16x16_bf16)
    return __builtin_amdgcn_mfma_f32_16x16x16_bf16(a, b, c, 0, 0, 0);
#else
    s16x4 as = __builtin_bit_cast(s16x4, a);
    s16x4 bs = __builtin_bit_cast(s16x4, b);
    return __builtin_amdgcn_mfma_f32_16x16x16bf16_1k(as, bs, c, 0, 0, 0);
#endif
}

__device__ __forceinline__ float fast_exp2(float x) {
#if __has_builtin(__builtin_amdgcn_exp2f)
    return __builtin_amdgcn_exp2f(x);
#else
    return exp2f(x);
#endif
}

// ---- fused prep: mask bitpack (0..8191), K cvt+swz (8192..8447), V^T (8448..8703)
__global__ __launch_bounds__(256)
void prep_all(const float* __restrict__ XK, const float* __restrict__ XV,
              const int* __restrict__ mask, bf16* __restrict__ Kb,
              bf16* __restrict__ Vtb, u64* __restrict__ bits)
{
    const int bid = blockIdx.x;
    const int tid = threadIdx.x;
    if (bid < 8192) {
        int wv = bid * 4 + (tid >> 6);
        int lane = tid & 63;
        size_t base = (size_t)wv * 256;
        #pragma unroll
        for (int s = 0; s < 4; ++s) {
            int m = mask[base + s * 64 + lane];
            u64 bal = __ballot(m != 0);
            if (lane == 0) bits[(size_t)wv * 4 + s] = bal;
        }
    } else if (bid < 8448) {
        // K -> bf16, 16B chunks XOR-swizzled within each 256B row
        int gid = (bid - 8192) * 256 + tid;
        int row = gid >> 4;
        int j   = gid & 15;
        const float* src = XK + (size_t)row * 128 + j * 8;
        float4 v0 = *(const float4*)src;
        float4 v1 = *(const float4*)(src + 4);
        bf16x8 w;
        w[0] = (bf16)v0.x; w[1] = (bf16)v0.y; w[2] = (bf16)v0.z; w[3] = (bf16)v0.w;
        w[4] = (bf16)v1.x; w[5] = (bf16)v1.y; w[6] = (bf16)v1.z; w[7] = (bf16)v1.w;
        int jp = j ^ (row & 15);
        *(bf16x8*)(Kb + (size_t)row * 128 + jp * 8) = w;
    } else {
        // V^T tiles [tile][f][64k]; 4-elem group g (k=4g..4g+3) stored at g^(f&15)
        int idx  = bid - 8448;
        int tile = idx >> 2;
        int fq   = idx & 3;
        int f    = fq * 32 + (tid & 31);
        int j    = tid >> 5;                  // 0..7 -> k = 8j..8j+7
        int bb   = tile >> 5, kt = tile & 31;
        const float* src = XV + ((size_t)(bb * L_ + kt * 64 + j * 8)) * F_ + f;
        bf16x4 w0, w1;
        #pragma unroll
        for (int jj = 0; jj < 4; ++jj) {
            w0[jj] = (bf16)src[(size_t)jj * F_];
            w1[jj] = (bf16)src[(size_t)(4 + jj) * F_];
        }
        bf16* outp = Vtb + (size_t)tile * 8192 + f * 64;
        *(bf16x4*)(outp + (((2 * j) ^ (f & 15)) * 4)) = w0;
        *(bf16x4*)(outp + (((2 * j + 1) ^ (f & 15)) * 4)) = w1;
    }
}

// ---- main fused kernel: 512 thr / 8 waves; wave = (kh, msel) owns 32k x 16m;
//      ONE barrier + ONE vmcnt wait per K-iteration ----
__global__ __launch_bounds__(512, 4)
void attn_fused_kernel(const float* __restrict__ XQ, const bf16* __restrict__ Kb,
                       const bf16* __restrict__ Vtb, const u64* __restrict__ bits,
                       const float* __restrict__ WQ, const float* __restrict__ WK,
                       const float* __restrict__ WV, const float* __restrict__ Om,
                       float* __restrict__ out)
{
    __shared__ __align__(16) char smem[SMEM_BYTES];
    __shared__ __align__(16) float g_s[128];

    bf16* sK0 = (bf16*)smem;
    bf16* sK1 = (bf16*)(smem + 16384);
    bf16* sV0 = (bf16*)(smem + 32768);
    bf16* sV1 = (bf16*)(smem + 49152);
    float* lws = (float*)(smem + LWS_OFF);
    float* pOx = (float*)smem;                 // epilogue
    bf16* sOh  = (bf16*)(smem + SOH_OFF);      // epilogue
    bf16* sO2t = (bf16*)smem;                  // epilogue (after pOx consumed)

    const int tid  = threadIdx.x;
    const int wave = tid >> 6;        // 0..7
    const int lane = tid & 63;
    const int c    = lane & 15;
    const int quad = lane >> 4;
    const int qt = blockIdx.x, h = blockIdx.y, b = blockIdx.z;
    const int q0 = qt * QT;

    const int kh   = wave >> 2;       // k-half (32 k)
    const int msel = wave & 3;        // m-tile (16 q rows)
    const int fv  = tid & 127;        // epilogue staging
    const int grp = tid >> 7;         // 0..3

    // g = diag(WQ)*diag(WK)/sqrt(D) * log2(e)  (softmax exp via exp2)
    if (tid < 128) {
        float wq = WQ[(h * D_ + tid) * D_ + tid];
        float wk = WK[(h * D_ + tid) * D_ + tid];
        g_s[tid] = wq * wk * 0.12752230502179406f;
    }
    __syncthreads();

    const char* gK = (const char*)Kb + (size_t)(b * L_) * 256;       // 16 KB/tile
    const char* gV = (const char*)Vtb + (size_t)(b * NKT) * 16384;   // 16 KB/tile

    // DMA tile 0, then mask prefetch (order: DMAs oldest)
    dma16(gK + tid * 16, (char*)sK0 + tid * 16);
    dma16(gK + 8192 + tid * 16, (char*)sK0 + 8192 + tid * 16);
    dma16(gV + tid * 16, (char*)sV0 + tid * 16);
    dma16(gV + 8192 + tid * 16, (char*)sV0 + 8192 + tid * 16);

    const u64* mrow = bits + (size_t)(b * L_ + q0 + msel * 16 + c) * NKT;
    u64 mb_cur = mrow[0];

    // wave's Q m-tile as B-fragments (scaled by g, bf16), loop-invariant
    bf16x8 qfrag[4];
    {
        const float* qrow = XQ + (size_t)(b * L_ + q0 + msel * 16 + c) * D_;
        #pragma unroll
        for (int kc = 0; kc < 4; ++kc) {
            int d0 = kc * 32 + quad * 8;
            float4 v0 = *(const float4*)(qrow + d0);
            float4 v1 = *(const float4*)(qrow + d0 + 4);
            float4 g0 = *(const float4*)(g_s + d0);
            float4 g1 = *(const float4*)(g_s + d0 + 4);
            bf16x8 w;
            w[0] = (bf16)(v0.x * g0.x); w[1] = (bf16)(v0.y * g0.y);
            w[2] = (bf16)(v0.z * g0.z); w[3] = (bf16)(v0.w * g0.w);
            w[4] = (bf16)(v1.x * g1.x); w[5] = (bf16)(v1.y * g1.y);
            w[6] = (bf16)(v1.z * g1.z); w[7] = (bf16)(v1.w * g1.w);
            qfrag[kc] = w;
        }
    }

    f32x4 oacc[8];                     // partial O[16m][128f] over wave's 32k slices
    #pragma unroll
    for (int fi = 0; fi < 8; ++fi)
        #pragma unroll
        for (int r = 0; r < 4; ++r) oacc[fi][r] = 0.f;
    float lsum = 0.f;

    #pragma unroll 2
    for (int kt = 0; kt < NKT; ++kt) {
        bf16* sK  = (kt & 1) ? sK1 : sK0;
        bf16* sV  = (kt & 1) ? sV1 : sV0;
        bf16* sKn = (kt & 1) ? sK0 : sK1;
        bf16* sVn = (kt & 1) ? sV0 : sV1;

        // Own tile-kt DMAs (issued a full iteration ago) + mask drained.
        asm volatile("s_waitcnt vmcnt(0)" ::: "memory");
        // Barrier: tile kt resident block-wide AND all tile-(kt-1) reads done,
        // so issuing DMA into the other buffer after this point is safe.
        asm volatile("s_barrier" ::: "memory");

        if (kt + 1 < NKT) {
            const char* gkn = gK + (size_t)(kt + 1) * 16384;
            const char* gvn = gV + (size_t)(kt + 1) * 16384;
            dma16(gkn + tid * 16, (char*)sKn + tid * 16);
            dma16(gkn + 8192 + tid * 16, (char*)sKn + 8192 + tid * 16);
            dma16(gvn + tid * 16, (char*)sVn + tid * 16);
            dma16(gvn + 8192 + tid * 16, (char*)sVn + 8192 + tid * 16);
        }
        u64 mb_next = mrow[(kt + 1 < NKT) ? kt + 1 : kt];

        // S^T = K @ Qg^T : wave's 2 k-tiles (kh*2+kti), A from LDS, B in regs
        f32x4 tacc[2];
        #pragma unroll
        for (int kti = 0; kti < 2; ++kti)
            #pragma unroll
            for (int r = 0; r < 4; ++r) tacc[kti][r] = 0.f;

        #pragma unroll
        for (int kti = 0; kti < 2; ++kti) {
            const bf16* krow = sK + ((kh * 2 + kti) * 16 + c) * 128;
            #pragma unroll
            for (int kc = 0; kc < 4; ++kc) {
                bf16x8 kfrag = *(const bf16x8*)(krow + (((kc * 4 + quad) ^ c) * 8));
                tacc[kti] = mfma32(kfrag, qfrag[kc], tacc[kti]);
            }
        }

        // lane(c,quad) reg r = S^T[k = kh*32+kti*16+quad*4+r][m = msel*16+c]
        // -> exp2 -> DIRECTLY the A-operand of 16x16x16 MFMA (m=lane&15, k=quad*4+j)
        bf16x4 pfrag[2];
        #pragma unroll
        for (int kti = 0; kti < 2; ++kti) {
            #pragma unroll
            for (int r = 0; r < 4; ++r) {
                int pos = kh * 32 + kti * 16 + quad * 4 + r;
                float p = ((mb_cur >> pos) & 1ull) ? fast_exp2(tacc[kti][r]) : 0.f;
                lsum += p;
                pfrag[kti][r] = (bf16)p;
            }
        }

        // O_partial += P @ V over wave's 32 k (register P, LDS V)
        #pragma unroll
        for (int fi = 0; fi < 8; ++fi) {
            #pragma unroll
            for (int kti = 0; kti < 2; ++kti) {
                int g = kh * 8 + kti * 4 + quad;
                bf16x4 vfrag = *(const bf16x4*)(sV + (fi * 16 + c) * 64 + ((g ^ c) * 4));
                oacc[fi] = mfma16(pfrag[kti], vfrag, oacc[fi]);
            }
        }

        mb_cur = mb_next;
    }

    // publish per-wave row sums: lane c holds sum over wave's 32k after quad-reduce
    {
        float v = lsum;
        v += __shfl_xor(v, 16); v += __shfl_xor(v, 32);
        if (lane < 16) lws[wave * 16 + lane] = v;
    }
    if (tid < 128)
        g_s[tid] = WV[(h * F_ + tid) * F_ + tid];   // dv (g_s no longer needed)
    __syncthreads();   // main-loop LDS reads done; lws visible

    // kh=1 waves dump partial O to pOx
    if (kh == 1) {
        #pragma unroll
        for (int fi = 0; fi < 8; ++fi)
            #pragma unroll
            for (int r = 0; r < 4; ++r)
                pOx[(msel * 16 + quad * 4 + r) * POX_STRIDE + fi * 16 + c] = oacc[fi][r];
    }
    __syncthreads();

    // kh=0 waves: combine halves, normalize, write sOh (bf16)
    if (kh == 0) {
        float linv[4];
        #pragma unroll
        for (int r = 0; r < 4; ++r) {
            int m16 = quad * 4 + r;
            linv[r] = 1.0f / (lws[msel * 16 + m16] + lws[(4 + msel) * 16 + m16]);
        }
        #pragma unroll
        for (int fi = 0; fi < 8; ++fi)
            #pragma unroll
            for (int r = 0; r < 4; ++r) {
                int row = msel * 16 + quad * 4 + r;
                float v = (oacc[fi][r] + pOx[row * POX_STRIDE + fi * 16 + c]) * linv[r];
                sOh[row * SOH_STRIDE + fi * 16 + c] = (bf16)v;
            }
    }
    __syncthreads();   // pOx consumed -> sO2t region free

    // stage O2^T: sO2t[f][f'] = O[h*128+f'][f] * dv[f']
    #pragma unroll
    for (int i = 0; i < 8; ++i) {
        int fp4 = grp * 32 + i * 4;
        bf16x4 w;
        #pragma unroll
        for (int j = 0; j < 4; ++j) {
            int x = fp4 + j;
            w[j] = (bf16)(Om[(h * F_ + x) * F_ + fv] * g_s[x]);
        }
        *(bf16x4*)(sO2t + fv * SO2_STRIDE + fp4) = w;
    }
    __syncthreads();

    // out_partial = Oh @ O2 (64x128x128): wave (pm, pf), atomic over heads
    const int pm = wave & 3;
    const int pf = wave >> 2;
    bf16x8 afr[4];
    const bf16* ohrow = sOh + (pm * 16 + c) * SOH_STRIDE;
    #pragma unroll
    for (int kc = 0; kc < 4; ++kc)
        afr[kc] = *(const bf16x8*)(ohrow + kc * 32 + quad * 8);

    #pragma unroll
    for (int nt = 0; nt < 4; ++nt) {
        f32x4 pacc;
        #pragma unroll
        for (int r = 0; r < 4; ++r) pacc[r] = 0.f;
        const bf16* orow = sO2t + ((pf * 4 + nt) * 16 + c) * SO2_STRIDE;
        #pragma unroll
        for (int kc = 0; kc < 4; ++kc) {
            bf16x8 bfrag = *(const bf16x8*)(orow + kc * 32 + quad * 8);
            pacc = mfma32(afr[kc], bfrag, pacc);
        }
        #pragma unroll
        for (int r = 0; r < 4; ++r) {
            int qg = q0 + pm * 16 + quad * 4 + r;
            atomicAdd(out + ((size_t)(b * L_ + qg) * F_ + (pf * 4 + nt) * 16 + c), pacc[r]);
        }
    }
}

extern "C" void kernel_launch(void* const* d_in, const int* in_sizes, int n_in,
                              void* d_out, int out_size, void* d_ws, size_t ws_size,
                              hipStream_t stream) {
    const float* XQ   = (const float*)d_in[0];
    const float* XK   = (const float*)d_in[1];
    const float* XV   = (const float*)d_in[2];
    const int*   mask = (const int*)d_in[3];
    const float* WQ   = (const float*)d_in[4];
    const float* WK   = (const float*)d_in[5];
    const float* WV   = (const float*)d_in[6];
    const float* Om   = (const float*)d_in[7];
    float* out = (float*)d_out;

    char* ws = (char*)d_ws;
    bf16* Kb   = (bf16*)(ws + WS_KB);
    bf16* Vtb  = (bf16*)(ws + WS_VT);
    u64*  bits = (u64*)(ws + WS_MB);

    prep_all<<<8704, 256, 0, stream>>>(XK, XV, mask, Kb, Vtb, bits);
    hipMemsetAsync(out, 0, (size_t)out_size * sizeof(float), stream);

    dim3 grid(L_ / QT, H_, B_);
    attn_fused_kernel<<<grid, 512, 0, stream>>>(XQ, Kb, Vtb, bits, WQ, WK, WV, Om, out);
}